// Round 11
// baseline (411.182 us; speedup 1.0000x reference)
//
#include <hip/hip_runtime.h>
#include <hip/hip_bf16.h>

typedef short short8 __attribute__((ext_vector_type(8)));
typedef float f32x4 __attribute__((ext_vector_type(4)));

#define S_   64
#define NL_  5000
#define PD_  1024
#define LD_  768
#define DIM_ 512
#define OD_  512

#define BK     32
#define KSTEPS 16          // DIM_/BK
#define NT_M   79          // ceil(5000/64) n-tiles for main
#define HL_RT  157         // ceil(5000/32) row-tiles for hl

__device__ __forceinline__ ushort f2bf(float f) {
    union { float f; unsigned u; } v; v.f = f;
    unsigned r = v.u + 0x7fffu + ((v.u >> 16) & 1u);   // RNE
    return (ushort)(r >> 16);
}
__device__ __forceinline__ float bf2f(ushort h) {
    union { unsigned u; float f; } v; v.u = ((unsigned)h) << 16;
    return v.f;
}

// ---- coalesced small GEMM: C[s][o0..o0+7] = A[64][K] @ W[.][K]^T (+bias) ---
__device__ __forceinline__ void proj8(
    float* Af /* [64][258] */, const float* __restrict__ A, int lda, int K,
    const float* __restrict__ W, int ldw, const float* __restrict__ bias,
    float* __restrict__ C, int o0, int t) {
    const int s = t & 63, og = t >> 6;
    const int oA = o0 + og * 2, oB = oA + 1;
    float acc0 = 0.f, acc1 = 0.f;
    for (int ck = 0; ck < K; ck += 256) {
        __syncthreads();
#pragma unroll
        for (int it = 0; it < 16; it++) {
            int r = it * 4 + (t >> 6);
            float4 v = *(const float4*)(A + (size_t)r * lda + ck + (t & 63) * 4);
            *(float4*)(Af + r * 258 + (t & 63) * 4) = v;
        }
        __syncthreads();
        const float* w0 = W + (size_t)oA * ldw + ck;
        const float* w1 = W + (size_t)oB * ldw + ck;
        const float* ar = Af + s * 258;
#pragma unroll 8
        for (int k4 = 0; k4 < 64; k4++) {
            f32x4 a4 = *(const f32x4*)(ar + k4 * 4);
            float4 v0 = *(const float4*)(w0 + k4 * 4);
            float4 v1 = *(const float4*)(w1 + k4 * 4);
            acc0 += a4[0] * v0.x + a4[1] * v0.y + a4[2] * v0.z + a4[3] * v0.w;
            acc1 += a4[0] * v1.x + a4[1] * v1.y + a4[2] * v1.z + a4[3] * v1.w;
        }
    }
    C[s * DIM_ + oA] = acc0 + (bias ? bias[oA] : 0.f);
    C[s * DIM_ + oB] = acc1 + (bias ? bias[oB] : 0.f);
}

// ==== pre-pass 1: {W2 panel (MFMA-fragment order) | M_lT | P_e} =============
// Panel: per kt (32KB), per o-group og=o>>4 (1KB), lane l = kslot*16+(o&15)
// at +l*16 -> B fragment read in-loop = one coalesced 1KB per (wave,frag).
__global__ __launch_bounds__(256) void k_pre1(
    const float* __restrict__ W2, const float* __restrict__ W_l,
    const float* __restrict__ W1, const float* __restrict__ P_f,
    const float* __restrict__ W_p,
    char* __restrict__ panel, ushort* __restrict__ MlT, float* __restrict__ P_e) {
    __shared__ float lbuf[64 * 258];       // 66048 B (union: w1r uses 16KB)
    int b = blockIdx.x, t = threadIdx.x;
    if (b < 128) {
        int c = b * 256 + t;                   // 32768 16B-chunks
        int o = c >> 6, rem = c & 63, kt = rem >> 2, kslot = rem & 3;
        const float* src = W2 + o * DIM_ + kt * BK + kslot * 8;
        float4 v0 = *(const float4*)src;
        float4 v1 = *(const float4*)(src + 4);
        union { ushort u[8]; short8 v; } pk;
        pk.u[0] = f2bf(v0.x); pk.u[1] = f2bf(v0.y); pk.u[2] = f2bf(v0.z); pk.u[3] = f2bf(v0.w);
        pk.u[4] = f2bf(v1.x); pk.u[5] = f2bf(v1.y); pk.u[6] = f2bf(v1.z); pk.u[7] = f2bf(v1.w);
        *(short8*)(panel + kt * 32768 + (o >> 4) * 1024 + kslot * 256 + (o & 15) * 16) = pk.v;
    } else if (b < 320) {
        float (*w1r)[DIM_] = (float (*)[DIM_])lbuf;
        int bx = b - 128;
        int o0 = (bx / 3) * 8;
        int ld = (bx % 3) * 256 + t;
        for (int i = t; i < 8 * DIM_; i += 256)
            w1r[i >> 9][i & 511] = W1[(o0 + (i >> 9)) * (2 * DIM_) + DIM_ + (i & 511)];
        __syncthreads();
        float acc[8] = {};
        for (int dim = 0; dim < DIM_; dim++) {
            float wl = W_l[dim * LD_ + ld];
#pragma unroll
            for (int oi = 0; oi < 8; oi++) acc[oi] += w1r[oi][dim] * wl;
        }
#pragma unroll
        for (int oi = 0; oi < 8; oi++) MlT[(o0 + oi) * LD_ + ld] = f2bf(acc[oi]);
    } else {
        proj8(lbuf, P_f, PD_, PD_, W_p, PD_, nullptr, P_e, (b - 320) * 8, t);
    }
}

// ==== pre-pass 2: {hpb = P_e @ W1p.T + b1 | hlB = bf16(emb[L]) @ MlT} =======
__global__ __launch_bounds__(256) void k_pre2(
    const float* __restrict__ P_e, const float* __restrict__ W1,
    const float* __restrict__ b1, const float* __restrict__ emb,
    const int* __restrict__ L, const ushort* __restrict__ MlT,
    float* __restrict__ hpb, ushort* __restrict__ hlB) {
    __shared__ float lbuf[64 * 258];
    int b = blockIdx.x, t = threadIdx.x;
    if (b < 64) {
        proj8(lbuf, P_e, DIM_, DIM_, W1, 2 * DIM_, b1, hpb, b * 8, t);
    } else {
        int hb = b - 64;                      // 0..313
        int rblk = hb % HL_RT, oh = hb / HL_RT;
        int r0 = rblk * 32;
        int w = t >> 6, l = t & 63, lg = l >> 4, ll = l & 15;
        const float* arow[2];
#pragma unroll
        for (int mt = 0; mt < 2; mt++) {
            int r = r0 + mt * 16 + ll;
            if (r >= NL_) r = NL_ - 1;
            arow[mt] = emb + (size_t)L[r] * LD_ + lg * 8;
        }
        f32x4 acc[2][4] = {};
        for (int k = 0; k < LD_; k += 32) {
            short8 a[2], bf[4];
#pragma unroll
            for (int mt = 0; mt < 2; mt++) {
                float4 v0 = *(const float4*)(arow[mt] + k);
                float4 v1 = *(const float4*)(arow[mt] + k + 4);
                union { ushort u[8]; short8 v; } pk;
                pk.u[0] = f2bf(v0.x); pk.u[1] = f2bf(v0.y);
                pk.u[2] = f2bf(v0.z); pk.u[3] = f2bf(v0.w);
                pk.u[4] = f2bf(v1.x); pk.u[5] = f2bf(v1.y);
                pk.u[6] = f2bf(v1.z); pk.u[7] = f2bf(v1.w);
                a[mt] = pk.v;
            }
#pragma unroll
            for (int ot = 0; ot < 4; ot++) {
                int o = oh * 256 + w * 64 + ot * 16 + ll;
                bf[ot] = *(const short8*)(MlT + o * LD_ + k + lg * 8);
            }
#pragma unroll
            for (int mt = 0; mt < 2; mt++)
#pragma unroll
                for (int ot = 0; ot < 4; ot++)
                    acc[mt][ot] = __builtin_amdgcn_mfma_f32_16x16x32_bf16(a[mt], bf[ot], acc[mt][ot], 0, 0, 0);
        }
#pragma unroll
        for (int mt = 0; mt < 2; mt++)
#pragma unroll
            for (int ot = 0; ot < 4; ot++)
#pragma unroll
                for (int reg = 0; reg < 4; reg++) {
                    int r = r0 + mt * 16 + lg * 4 + reg;
                    if (r < NL_)
                        hlB[(size_t)r * DIM_ + oh * 256 + w * 64 + ot * 16 + ll] = f2bf(acc[mt][ot][reg]);
                }
    }
}

// ==== main: BM=128 x BN=512, BK=32 — FULLY DECOUPLED WAVES ==================
// 8 waves (2M x 4N), wave tile 64x128, acc[4][8] (128 AGPR).
// NO barrier / manual waitcnt in the K-loop: each wave packs its OWN private
// A slice (it owns one s-row: rows (s0+wr, n0+0..63)) into a private 4KB LDS
// dbuf. Same-wave DS ordering + compiler lgkm waits are the only sync.
// A-slice layout [chunk c][row r] @ c*1024 + r*16:
//   write (lane l = row l, 4 chunks): 1KB contiguous per instr, conflict-free
//   read  (a[mt]: lane(lg,ll) @ lg*1024 + (mt*16+ll)*16): 4x256B contiguous.
// B: fragment-ordered panel, register quads bq0/bq1 (r10 path, unchanged).
__global__ __launch_bounds__(512, 2) void k_main2(
    const ushort* __restrict__ hlB, const float* __restrict__ hpb,
    const char* __restrict__ panel, const float* __restrict__ b2,
    const float* __restrict__ W3, const float* __restrict__ b3,
    float* __restrict__ out) {
    __shared__ f32x4 ldsv[4096];            // 65536 B: 8 waves x 2 bufs x 4KB
    char* lds = (char*)ldsv;
    const int t = threadIdx.x;
    const int n0 = blockIdx.x * 64, s0 = blockIdx.y * 2;
    const int w = t >> 6, lane = t & 63, lg = lane >> 4, ll = lane & 15;
    const int wr = w >> 2, wc = w & 3;      // 2M x 4N wave grid

    // per-wave private A sources: lane l owns row (s0+wr, n0+l)
    int an = n0 + lane; if (an >= NL_) an = NL_ - 1;
    const ushort* hlsrc = hlB + (size_t)an * DIM_;            // 64B per k-step
    const float*  hpsrc = hpb + (s0 + wr) * DIM_;             // wave-uniform
    char* slice = lds + w * 8192;                             // [2][4][64][16B]
    const int rdbase = lg * 1024 + ll * 16;                   // + mt*256

    const char* bbase = panel + (wc * 8) * 1024 + lane * 16;

    f32x4 acc[4][8] = {};

    // pack A k-tile kt into buf: 4 chunks of 8 elems (relu(hl+hp) -> bf16)
    auto packA = [&](int kt, int buf) {
        char* dst = slice + buf * 4096;
#pragma unroll
        for (int c = 0; c < 4; c++) {
            short8 hv = *(const short8*)(hlsrc + kt * BK + c * 8);
            f32x4 p0 = *(const f32x4*)(hpsrc + kt * BK + c * 8);
            f32x4 p1 = *(const f32x4*)(hpsrc + kt * BK + c * 8 + 4);
            float x[8];
#pragma unroll
            for (int e = 0; e < 4; e++) {
                float s0f = bf2f((ushort)hv[e]) + p0[e];
                float s1f = bf2f((ushort)hv[4 + e]) + p1[e];
                x[e]     = s0f > 0.f ? s0f : 0.f;
                x[4 + e] = s1f > 0.f ? s1f : 0.f;
            }
            union { __hip_bfloat162 h2[4]; short8 v; } pk;
#pragma unroll
            for (int e = 0; e < 4; e++)
                pk.h2[e] = __float22bfloat162_rn(make_float2(x[2 * e], x[2 * e + 1]));
            *(short8*)(dst + c * 1024 + lane * 16) = pk.v;
        }
    };

    // ---- prologue: pack A(0) (private -> no barrier); preload B quad ----
    packA(0, 0);
    short8 bq0[4], bq1[4];
#pragma unroll
    for (int j = 0; j < 4; j++) bq0[j] = *(const short8*)(bbase + j * 1024);

    for (int kt = 0; kt < KSTEPS; kt++) {
        const char* bkt = bbase + kt * 32768;
        // A fragments for this k-step (own slice, written last iteration;
        // same-wave DS queue is in-order -> RAW safe, compiler adds lgkm wait)
        const char* A = slice + (kt & 1) * 4096;
        short8 a[4];
#pragma unroll
        for (int mt = 0; mt < 4; mt++) a[mt] = *(const short8*)(A + rdbase + mt * 256);
        // issue quad (kt,1) while computing quad (kt,0)
#pragma unroll
        for (int j = 0; j < 4; j++) bq1[j] = *(const short8*)(bkt + 4096 + j * 1024);
        __builtin_amdgcn_s_setprio(1);
#pragma unroll
        for (int mt = 0; mt < 4; mt++)
#pragma unroll
            for (int j = 0; j < 4; j++)
                acc[mt][j] = __builtin_amdgcn_mfma_f32_16x16x32_bf16(a[mt], bq0[j], acc[mt][j], 0, 0, 0);
        __builtin_amdgcn_s_setprio(0);
        // issue quad (kt+1,0) while computing quad (kt,1)
        if (kt + 1 < KSTEPS)
#pragma unroll
            for (int j = 0; j < 4; j++) bq0[j] = *(const short8*)(bkt + 32768 + j * 1024);
        __builtin_amdgcn_s_setprio(1);
#pragma unroll
        for (int mt = 0; mt < 4; mt++)
#pragma unroll
            for (int j = 0; j < 4; j++)
                acc[mt][4 + j] = __builtin_amdgcn_mfma_f32_16x16x32_bf16(a[mt], bq1[j], acc[mt][4 + j], 0, 0, 0);
        __builtin_amdgcn_s_setprio(0);
        if (kt + 1 < KSTEPS) packA(kt + 1, (kt + 1) & 1);     // own slice only
    }

    // ---- epilogue: relu(acc+b2)*W3, reduce over o; direct out write ----
    __syncthreads();                        // all waves done with LDS slices
    float* logit = (float*)lds;
    if (t < 128) logit[t] = 0.f;
    __syncthreads();
#pragma unroll
    for (int mt = 0; mt < 4; mt++) {
        float p4[4] = { 0.f, 0.f, 0.f, 0.f };
#pragma unroll
        for (int ot = 0; ot < 8; ot++) {
            int o = wc * 128 + ot * 16 + ll;
            float bb = b2[o], w3 = W3[o];
#pragma unroll
            for (int reg = 0; reg < 4; reg++) {
                float v = acc[mt][ot][reg] + bb;
                v = v > 0.f ? v : 0.f;
                p4[reg] += v * w3;
            }
        }
#pragma unroll
        for (int m = 1; m < 16; m <<= 1)
#pragma unroll
            for (int reg = 0; reg < 4; reg++) p4[reg] += __shfl_xor(p4[reg], m, 64);
        if (ll == 0)
#pragma unroll
            for (int reg = 0; reg < 4; reg++)
                atomicAdd(&logit[wr * 64 + mt * 16 + lg * 4 + reg], p4[reg]);
    }
    __syncthreads();
    if (t < 128) {
        int n = n0 + (t & 63);
        int s = s0 + (t >> 6);
        if (n < NL_) out[(size_t)s * NL_ + n] = logit[t] + b3[0];
    }
}

extern "C" void kernel_launch(void* const* d_in, const int* in_sizes, int n_in,
                              void* d_out, int out_size, void* d_ws, size_t ws_size,
                              hipStream_t stream) {
    const float* P_f = (const float*)d_in[0];
    const float* emb = (const float*)d_in[1];
    const float* W_p = (const float*)d_in[2];
    const float* W_l = (const float*)d_in[3];
    const float* W1  = (const float*)d_in[4];
    const float* b1  = (const float*)d_in[5];
    const float* W2  = (const float*)d_in[6];
    const float* b2  = (const float*)d_in[7];
    const float* W3  = (const float*)d_in[8];
    const float* b3  = (const float*)d_in[9];
    const int*   L   = (const int*)d_in[10];
    float* out = (float*)d_out;

    char* ws = (char*)d_ws;
    size_t off = 0;
    auto alloc = [&](size_t bytes) {
        void* p = ws + off;
        off = (off + bytes + 255) & ~(size_t)255;
        return p;
    };
    char*   panel = (char*)alloc((size_t)KSTEPS * 32768);            // 512 KB
    ushort* MlT   = (ushort*)alloc((size_t)OD_ * LD_ * 2);           // 768 KB
    float*  P_e   = (float*)alloc((size_t)S_ * DIM_ * 4);
    float*  hpb   = (float*)alloc((size_t)S_ * DIM_ * 4);
    ushort* hlB   = (ushort*)alloc((size_t)NL_ * DIM_ * 2);          // 5.12 MB

    k_pre1<<<384, 256, 0, stream>>>(W2, W_l, W1, P_f, W_p, panel, MlT, P_e);
    k_pre2<<<378, 256, 0, stream>>>(P_e, W1, b1, emb, L, MlT, hpb, hlB);
    k_main2<<<dim3(NT_M, 32), 512, 0, stream>>>(hlB, hpb, panel, b2, W3, b3, out);
}

// Round 12
// 362.340 us; speedup vs baseline: 1.1348x; 1.1348x over previous
//
#include <hip/hip_runtime.h>
#include <hip/hip_bf16.h>

typedef short short8 __attribute__((ext_vector_type(8)));
typedef float f32x4 __attribute__((ext_vector_type(4)));

#define S_   64
#define NL_  5000
#define PD_  1024
#define LD_  768
#define DIM_ 512
#define OD_  512

#define BK     32
#define KSTEPS 16          // DIM_/BK
#define NT_M   79          // ceil(5000/64) n-tiles for main
#define HL_RT  157         // ceil(5000/32) row-tiles for hl

__device__ __forceinline__ ushort f2bf(float f) {
    union { float f; unsigned u; } v; v.f = f;
    unsigned r = v.u + 0x7fffu + ((v.u >> 16) & 1u);   // RNE
    return (ushort)(r >> 16);
}
__device__ __forceinline__ float bf2f(ushort h) {
    union { unsigned u; float f; } v; v.u = ((unsigned)h) << 16;
    return v.f;
}

// ---- coalesced small GEMM: C[s][o0..o0+7] = A[64][K] @ W[.][K]^T (+bias) ---
__device__ __forceinline__ void proj8(
    float* Af /* [64][258] */, const float* __restrict__ A, int lda, int K,
    const float* __restrict__ W, int ldw, const float* __restrict__ bias,
    float* __restrict__ C, int o0, int t) {
    const int s = t & 63, og = t >> 6;
    const int oA = o0 + og * 2, oB = oA + 1;
    float acc0 = 0.f, acc1 = 0.f;
    for (int ck = 0; ck < K; ck += 256) {
        __syncthreads();
#pragma unroll
        for (int it = 0; it < 16; it++) {
            int r = it * 4 + (t >> 6);
            float4 v = *(const float4*)(A + (size_t)r * lda + ck + (t & 63) * 4);
            *(float4*)(Af + r * 258 + (t & 63) * 4) = v;
        }
        __syncthreads();
        const float* w0 = W + (size_t)oA * ldw + ck;
        const float* w1 = W + (size_t)oB * ldw + ck;
        const float* ar = Af + s * 258;
#pragma unroll 8
        for (int k4 = 0; k4 < 64; k4++) {
            f32x4 a4 = *(const f32x4*)(ar + k4 * 4);
            float4 v0 = *(const float4*)(w0 + k4 * 4);
            float4 v1 = *(const float4*)(w1 + k4 * 4);
            acc0 += a4[0] * v0.x + a4[1] * v0.y + a4[2] * v0.z + a4[3] * v0.w;
            acc1 += a4[0] * v1.x + a4[1] * v1.y + a4[2] * v1.z + a4[3] * v1.w;
        }
    }
    C[s * DIM_ + oA] = acc0 + (bias ? bias[oA] : 0.f);
    C[s * DIM_ + oB] = acc1 + (bias ? bias[oB] : 0.f);
}

// ==== pre-pass 1: {W2 panel (MFMA-fragment order) | M_lT | P_e} =============
// Panel: per kt (32KB), per o-group og=o>>4 (1KB), lane l = kslot*16+(o&15)
// at +l*16 -> B fragment read in-loop = one coalesced 1KB per (wave,frag).
__global__ __launch_bounds__(256) void k_pre1(
    const float* __restrict__ W2, const float* __restrict__ W_l,
    const float* __restrict__ W1, const float* __restrict__ P_f,
    const float* __restrict__ W_p,
    char* __restrict__ panel, ushort* __restrict__ MlT, float* __restrict__ P_e) {
    __shared__ float lbuf[64 * 258];       // 66048 B (union: w1r uses 16KB)
    int b = blockIdx.x, t = threadIdx.x;
    if (b < 128) {
        int c = b * 256 + t;                   // 32768 16B-chunks
        int o = c >> 6, rem = c & 63, kt = rem >> 2, kslot = rem & 3;
        const float* src = W2 + o * DIM_ + kt * BK + kslot * 8;
        float4 v0 = *(const float4*)src;
        float4 v1 = *(const float4*)(src + 4);
        union { ushort u[8]; short8 v; } pk;
        pk.u[0] = f2bf(v0.x); pk.u[1] = f2bf(v0.y); pk.u[2] = f2bf(v0.z); pk.u[3] = f2bf(v0.w);
        pk.u[4] = f2bf(v1.x); pk.u[5] = f2bf(v1.y); pk.u[6] = f2bf(v1.z); pk.u[7] = f2bf(v1.w);
        *(short8*)(panel + kt * 32768 + (o >> 4) * 1024 + kslot * 256 + (o & 15) * 16) = pk.v;
    } else if (b < 320) {
        float (*w1r)[DIM_] = (float (*)[DIM_])lbuf;
        int bx = b - 128;
        int o0 = (bx / 3) * 8;
        int ld = (bx % 3) * 256 + t;
        for (int i = t; i < 8 * DIM_; i += 256)
            w1r[i >> 9][i & 511] = W1[(o0 + (i >> 9)) * (2 * DIM_) + DIM_ + (i & 511)];
        __syncthreads();
        float acc[8] = {};
        for (int dim = 0; dim < DIM_; dim++) {
            float wl = W_l[dim * LD_ + ld];
#pragma unroll
            for (int oi = 0; oi < 8; oi++) acc[oi] += w1r[oi][dim] * wl;
        }
#pragma unroll
        for (int oi = 0; oi < 8; oi++) MlT[(o0 + oi) * LD_ + ld] = f2bf(acc[oi]);
    } else {
        proj8(lbuf, P_f, PD_, PD_, W_p, PD_, nullptr, P_e, (b - 320) * 8, t);
    }
}

// ==== pre-pass 2: {hpb = P_e @ W1p.T + b1 | hlB = bf16(emb[L]) @ MlT} =======
__global__ __launch_bounds__(256) void k_pre2(
    const float* __restrict__ P_e, const float* __restrict__ W1,
    const float* __restrict__ b1, const float* __restrict__ emb,
    const int* __restrict__ L, const ushort* __restrict__ MlT,
    float* __restrict__ hpb, ushort* __restrict__ hlB) {
    __shared__ float lbuf[64 * 258];
    int b = blockIdx.x, t = threadIdx.x;
    if (b < 64) {
        proj8(lbuf, P_e, DIM_, DIM_, W1, 2 * DIM_, b1, hpb, b * 8, t);
    } else {
        int hb = b - 64;                      // 0..313
        int rblk = hb % HL_RT, oh = hb / HL_RT;
        int r0 = rblk * 32;
        int w = t >> 6, l = t & 63, lg = l >> 4, ll = l & 15;
        const float* arow[2];
#pragma unroll
        for (int mt = 0; mt < 2; mt++) {
            int r = r0 + mt * 16 + ll;
            if (r >= NL_) r = NL_ - 1;
            arow[mt] = emb + (size_t)L[r] * LD_ + lg * 8;
        }
        f32x4 acc[2][4] = {};
        for (int k = 0; k < LD_; k += 32) {
            short8 a[2], bf[4];
#pragma unroll
            for (int mt = 0; mt < 2; mt++) {
                float4 v0 = *(const float4*)(arow[mt] + k);
                float4 v1 = *(const float4*)(arow[mt] + k + 4);
                union { ushort u[8]; short8 v; } pk;
                pk.u[0] = f2bf(v0.x); pk.u[1] = f2bf(v0.y);
                pk.u[2] = f2bf(v0.z); pk.u[3] = f2bf(v0.w);
                pk.u[4] = f2bf(v1.x); pk.u[5] = f2bf(v1.y);
                pk.u[6] = f2bf(v1.z); pk.u[7] = f2bf(v1.w);
                a[mt] = pk.v;
            }
#pragma unroll
            for (int ot = 0; ot < 4; ot++) {
                int o = oh * 256 + w * 64 + ot * 16 + ll;
                bf[ot] = *(const short8*)(MlT + o * LD_ + k + lg * 8);
            }
#pragma unroll
            for (int mt = 0; mt < 2; mt++)
#pragma unroll
                for (int ot = 0; ot < 4; ot++)
                    acc[mt][ot] = __builtin_amdgcn_mfma_f32_16x16x32_bf16(a[mt], bf[ot], acc[mt][ot], 0, 0, 0);
        }
#pragma unroll
        for (int mt = 0; mt < 2; mt++)
#pragma unroll
            for (int ot = 0; ot < 4; ot++)
#pragma unroll
                for (int reg = 0; reg < 4; reg++) {
                    int r = r0 + mt * 16 + lg * 4 + reg;
                    if (r < NL_)
                        hlB[(size_t)r * DIM_ + oh * 256 + w * 64 + ot * 16 + ll] = f2bf(acc[mt][ot][reg]);
                }
    }
}

// ==== main: BM=128 x BN=512 — FRAGMENT-DIRECT A, ZERO BARRIERS ==============
// 8 waves (2M x 4N), wave tile 64x128, acc[4][8] (128 AGPR).
// A: each lane loads its MFMA fragment data straight from hlB (16 lines/instr:
// 16 rows x 64B, lg=0..3 split each row's 64B) + lg-broadcast hp, packs
// relu(hl+hp)->bf16 in registers. No LDS, no barriers, no waitcnt in K-loop;
// waves fully independent (r11's failure was 64-line row-slice loads + LDS
// round-trip; fragment-direct is 4x fewer lines and skips LDS).
// B: fragment-ordered panel, register quads bq0/bq1 (r10 path, unchanged).
__global__ __launch_bounds__(512, 2) void k_main2(
    const ushort* __restrict__ hlB, const float* __restrict__ hpb,
    const char* __restrict__ panel, const float* __restrict__ b2,
    const float* __restrict__ W3, const float* __restrict__ b3,
    float* __restrict__ out) {
    __shared__ float logit[128];
    const int t = threadIdx.x;
    const int n0 = blockIdx.x * 64, s0 = blockIdx.y * 2;
    const int w = t >> 6, lane = t & 63, lg = lane >> 4, ll = lane & 15;
    const int wr = w >> 2, wc = w & 3;      // 2M x 4N wave grid

    // per-fragment A row pointers (clamped); +lg*8 baked in
    const ushort* hlrow[4];
#pragma unroll
    for (int mt = 0; mt < 4; mt++) {
        int n = n0 + mt * 16 + ll; if (n >= NL_) n = NL_ - 1;
        hlrow[mt] = hlB + (size_t)n * DIM_ + lg * 8;
    }
    const float* hpsrc = hpb + (s0 + wr) * DIM_ + lg * 8;   // lg-broadcast
    const char* bbase = panel + (wc * 8) * 1024 + lane * 16;

    f32x4 acc[4][8] = {};

    auto packFrag = [&](short8 hv, f32x4 hp0, f32x4 hp1) -> short8 {
        float x[8];
#pragma unroll
        for (int e = 0; e < 4; e++) {
            float a0 = bf2f((ushort)hv[e]) + hp0[e];
            float a1 = bf2f((ushort)hv[4 + e]) + hp1[e];
            x[e]     = a0 > 0.f ? a0 : 0.f;
            x[4 + e] = a1 > 0.f ? a1 : 0.f;
        }
        union { __hip_bfloat162 h2[4]; short8 v; } pk;
#pragma unroll
        for (int e = 0; e < 4; e++)
            pk.h2[e] = __float22bfloat162_rn(make_float2(x[2 * e], x[2 * e + 1]));
        return pk.v;
    };

    // ---- prologue: raw A (kt=0) + B quad (kt=0, half 0) ----
    short8 hlr[4];
#pragma unroll
    for (int mt = 0; mt < 4; mt++) hlr[mt] = *(const short8*)(hlrow[mt]);
    f32x4 hp0 = *(const f32x4*)(hpsrc);
    f32x4 hp1 = *(const f32x4*)(hpsrc + 4);
    short8 bq0[4], bq1[4];
#pragma unroll
    for (int j = 0; j < 4; j++) bq0[j] = *(const short8*)(bbase + j * 1024);

#pragma unroll 2
    for (int kt = 0; kt < KSTEPS; kt++) {
        const char* bkt = bbase + kt * 32768;
        // pack this k-step's A fragments (consumes hlr/hp)
        short8 a[4];
#pragma unroll
        for (int mt = 0; mt < 4; mt++) a[mt] = packFrag(hlr[mt], hp0, hp1);
        // preload next k-step's raw A (long latency, hidden under MFMAs)
        if (kt + 1 < KSTEPS) {
#pragma unroll
            for (int mt = 0; mt < 4; mt++)
                hlr[mt] = *(const short8*)(hlrow[mt] + (kt + 1) * BK);
            hp0 = *(const f32x4*)(hpsrc + (kt + 1) * BK);
            hp1 = *(const f32x4*)(hpsrc + (kt + 1) * BK + 4);
        }
        // B half 1 while computing half 0
#pragma unroll
        for (int j = 0; j < 4; j++) bq1[j] = *(const short8*)(bkt + 4096 + j * 1024);
        __builtin_amdgcn_s_setprio(1);
#pragma unroll
        for (int mt = 0; mt < 4; mt++)
#pragma unroll
            for (int j = 0; j < 4; j++)
                acc[mt][j] = __builtin_amdgcn_mfma_f32_16x16x32_bf16(a[mt], bq0[j], acc[mt][j], 0, 0, 0);
        __builtin_amdgcn_s_setprio(0);
        if (kt + 1 < KSTEPS)
#pragma unroll
            for (int j = 0; j < 4; j++) bq0[j] = *(const short8*)(bkt + 32768 + j * 1024);
        __builtin_amdgcn_s_setprio(1);
#pragma unroll
        for (int mt = 0; mt < 4; mt++)
#pragma unroll
            for (int j = 0; j < 4; j++)
                acc[mt][4 + j] = __builtin_amdgcn_mfma_f32_16x16x32_bf16(a[mt], bq1[j], acc[mt][4 + j], 0, 0, 0);
        __builtin_amdgcn_s_setprio(0);
    }

    // ---- epilogue: relu(acc+b2)*W3, reduce over o; direct out write ----
    if (t < 128) logit[t] = 0.f;
    __syncthreads();
#pragma unroll
    for (int mt = 0; mt < 4; mt++) {
        float p4[4] = { 0.f, 0.f, 0.f, 0.f };
#pragma unroll
        for (int ot = 0; ot < 8; ot++) {
            int o = wc * 128 + ot * 16 + ll;
            float bb = b2[o], w3 = W3[o];
#pragma unroll
            for (int reg = 0; reg < 4; reg++) {
                float v = acc[mt][ot][reg] + bb;
                v = v > 0.f ? v : 0.f;
                p4[reg] += v * w3;
            }
        }
#pragma unroll
        for (int m = 1; m < 16; m <<= 1)
#pragma unroll
            for (int reg = 0; reg < 4; reg++) p4[reg] += __shfl_xor(p4[reg], m, 64);
        if (ll == 0)
#pragma unroll
            for (int reg = 0; reg < 4; reg++)
                atomicAdd(&logit[wr * 64 + mt * 16 + lg * 4 + reg], p4[reg]);
    }
    __syncthreads();
    if (t < 128) {
        int n = n0 + (t & 63);
        int s = s0 + (t >> 6);
        if (n < NL_) out[(size_t)s * NL_ + n] = logit[t] + b3[0];
    }
}

extern "C" void kernel_launch(void* const* d_in, const int* in_sizes, int n_in,
                              void* d_out, int out_size, void* d_ws, size_t ws_size,
                              hipStream_t stream) {
    const float* P_f = (const float*)d_in[0];
    const float* emb = (const float*)d_in[1];
    const float* W_p = (const float*)d_in[2];
    const float* W_l = (const float*)d_in[3];
    const float* W1  = (const float*)d_in[4];
    const float* b1  = (const float*)d_in[5];
    const float* W2  = (const float*)d_in[6];
    const float* b2  = (const float*)d_in[7];
    const float* W3  = (const float*)d_in[8];
    const float* b3  = (const float*)d_in[9];
    const int*   L   = (const int*)d_in[10];
    float* out = (float*)d_out;

    char* ws = (char*)d_ws;
    size_t off = 0;
    auto alloc = [&](size_t bytes) {
        void* p = ws + off;
        off = (off + bytes + 255) & ~(size_t)255;
        return p;
    };
    char*   panel = (char*)alloc((size_t)KSTEPS * 32768);            // 512 KB
    ushort* MlT   = (ushort*)alloc((size_t)OD_ * LD_ * 2);           // 768 KB
    float*  P_e   = (float*)alloc((size_t)S_ * DIM_ * 4);
    float*  hpb   = (float*)alloc((size_t)S_ * DIM_ * 4);
    ushort* hlB   = (ushort*)alloc((size_t)NL_ * DIM_ * 2);          // 5.12 MB

    k_pre1<<<384, 256, 0, stream>>>(W2, W_l, W1, P_f, W_p, panel, MlT, P_e);
    k_pre2<<<378, 256, 0, stream>>>(P_e, W1, b1, emb, L, MlT, hpb, hlB);
    k_main2<<<dim3(NT_M, 32), 512, 0, stream>>>(hlB, hpb, panel, b2, W3, b3, out);
}

// Round 13
// 259.308 us; speedup vs baseline: 1.5857x; 1.3973x over previous
//
#include <hip/hip_runtime.h>
#include <hip/hip_bf16.h>

typedef short short8 __attribute__((ext_vector_type(8)));
typedef float f32x4 __attribute__((ext_vector_type(4)));

#define S_   64
#define NL_  5000
#define PD_  1024
#define LD_  768
#define DIM_ 512
#define OD_  512

#define BK     32          // panel/pack granularity (unchanged layouts)
#define KT2    8           // main-loop iterations, 64-wide K each
#define KSTEPS 16          // DIM_/BK
#define NT_M   79          // ceil(5000/64) n-tiles for main
#define HL_RT  157         // ceil(5000/32) row-tiles for hl

__device__ __forceinline__ ushort f2bf(float f) {
    union { float f; unsigned u; } v; v.f = f;
    unsigned r = v.u + 0x7fffu + ((v.u >> 16) & 1u);   // RNE
    return (ushort)(r >> 16);
}
__device__ __forceinline__ float bf2f(ushort h) {
    union { unsigned u; float f; } v; v.u = ((unsigned)h) << 16;
    return v.f;
}
// XOR swizzle for 64B-stride row tiles: conflict-free for packA write
// (4 lanes/row x 4 kslots) and the 16-row x 4-kslot fragment read (measured
// 0 conflicts r6/r9/r10). swz(row+16,k) == swz(row,k)+1024.
__device__ __forceinline__ int swz(int row, int kslot) {
    return (row * 64 + kslot * 16) ^ (((row >> 1) & 7) << 4);
}

// ---- coalesced small GEMM: C[s][o0..o0+7] = A[64][K] @ W[.][K]^T (+bias) ---
__device__ __forceinline__ void proj8(
    float* Af /* [64][258] */, const float* __restrict__ A, int lda, int K,
    const float* __restrict__ W, int ldw, const float* __restrict__ bias,
    float* __restrict__ C, int o0, int t) {
    const int s = t & 63, og = t >> 6;
    const int oA = o0 + og * 2, oB = oA + 1;
    float acc0 = 0.f, acc1 = 0.f;
    for (int ck = 0; ck < K; ck += 256) {
        __syncthreads();
#pragma unroll
        for (int it = 0; it < 16; it++) {
            int r = it * 4 + (t >> 6);
            float4 v = *(const float4*)(A + (size_t)r * lda + ck + (t & 63) * 4);
            *(float4*)(Af + r * 258 + (t & 63) * 4) = v;
        }
        __syncthreads();
        const float* w0 = W + (size_t)oA * ldw + ck;
        const float* w1 = W + (size_t)oB * ldw + ck;
        const float* ar = Af + s * 258;
#pragma unroll 8
        for (int k4 = 0; k4 < 64; k4++) {
            f32x4 a4 = *(const f32x4*)(ar + k4 * 4);
            float4 v0 = *(const float4*)(w0 + k4 * 4);
            float4 v1 = *(const float4*)(w1 + k4 * 4);
            acc0 += a4[0] * v0.x + a4[1] * v0.y + a4[2] * v0.z + a4[3] * v0.w;
            acc1 += a4[0] * v1.x + a4[1] * v1.y + a4[2] * v1.z + a4[3] * v1.w;
        }
    }
    C[s * DIM_ + oA] = acc0 + (bias ? bias[oA] : 0.f);
    C[s * DIM_ + oB] = acc1 + (bias ? bias[oB] : 0.f);
}

// ==== pre-pass 1: {W2 panel (MFMA-fragment order) | M_lT | P_e} =============
__global__ __launch_bounds__(256) void k_pre1(
    const float* __restrict__ W2, const float* __restrict__ W_l,
    const float* __restrict__ W1, const float* __restrict__ P_f,
    const float* __restrict__ W_p,
    char* __restrict__ panel, ushort* __restrict__ MlT, float* __restrict__ P_e) {
    __shared__ float lbuf[64 * 258];       // 66048 B (union: w1r uses 16KB)
    int b = blockIdx.x, t = threadIdx.x;
    if (b < 128) {
        int c = b * 256 + t;                   // 32768 16B-chunks
        int o = c >> 6, rem = c & 63, kt = rem >> 2, kslot = rem & 3;
        const float* src = W2 + o * DIM_ + kt * BK + kslot * 8;
        float4 v0 = *(const float4*)src;
        float4 v1 = *(const float4*)(src + 4);
        union { ushort u[8]; short8 v; } pk;
        pk.u[0] = f2bf(v0.x); pk.u[1] = f2bf(v0.y); pk.u[2] = f2bf(v0.z); pk.u[3] = f2bf(v0.w);
        pk.u[4] = f2bf(v1.x); pk.u[5] = f2bf(v1.y); pk.u[6] = f2bf(v1.z); pk.u[7] = f2bf(v1.w);
        *(short8*)(panel + kt * 32768 + (o >> 4) * 1024 + kslot * 256 + (o & 15) * 16) = pk.v;
    } else if (b < 320) {
        float (*w1r)[DIM_] = (float (*)[DIM_])lbuf;
        int bx = b - 128;
        int o0 = (bx / 3) * 8;
        int ld = (bx % 3) * 256 + t;
        for (int i = t; i < 8 * DIM_; i += 256)
            w1r[i >> 9][i & 511] = W1[(o0 + (i >> 9)) * (2 * DIM_) + DIM_ + (i & 511)];
        __syncthreads();
        float acc[8] = {};
        for (int dim = 0; dim < DIM_; dim++) {
            float wl = W_l[dim * LD_ + ld];
#pragma unroll
            for (int oi = 0; oi < 8; oi++) acc[oi] += w1r[oi][dim] * wl;
        }
#pragma unroll
        for (int oi = 0; oi < 8; oi++) MlT[(o0 + oi) * LD_ + ld] = f2bf(acc[oi]);
    } else {
        proj8(lbuf, P_f, PD_, PD_, W_p, PD_, nullptr, P_e, (b - 320) * 8, t);
    }
}

// ==== pre-pass 2: {hpb = P_e @ W1p.T + b1 | hlB = bf16(emb[L]) @ MlT} =======
__global__ __launch_bounds__(256) void k_pre2(
    const float* __restrict__ P_e, const float* __restrict__ W1,
    const float* __restrict__ b1, const float* __restrict__ emb,
    const int* __restrict__ L, const ushort* __restrict__ MlT,
    float* __restrict__ hpb, ushort* __restrict__ hlB) {
    __shared__ float lbuf[64 * 258];
    int b = blockIdx.x, t = threadIdx.x;
    if (b < 64) {
        proj8(lbuf, P_e, DIM_, DIM_, W1, 2 * DIM_, b1, hpb, b * 8, t);
    } else {
        int hb = b - 64;                      // 0..313
        int rblk = hb % HL_RT, oh = hb / HL_RT;
        int r0 = rblk * 32;
        int w = t >> 6, l = t & 63, lg = l >> 4, ll = l & 15;
        const float* arow[2];
#pragma unroll
        for (int mt = 0; mt < 2; mt++) {
            int r = r0 + mt * 16 + ll;
            if (r >= NL_) r = NL_ - 1;
            arow[mt] = emb + (size_t)L[r] * LD_ + lg * 8;
        }
        f32x4 acc[2][4] = {};
        for (int k = 0; k < LD_; k += 32) {
            short8 a[2], bf[4];
#pragma unroll
            for (int mt = 0; mt < 2; mt++) {
                float4 v0 = *(const float4*)(arow[mt] + k);
                float4 v1 = *(const float4*)(arow[mt] + k + 4);
                union { ushort u[8]; short8 v; } pk;
                pk.u[0] = f2bf(v0.x); pk.u[1] = f2bf(v0.y);
                pk.u[2] = f2bf(v0.z); pk.u[3] = f2bf(v0.w);
                pk.u[4] = f2bf(v1.x); pk.u[5] = f2bf(v1.y);
                pk.u[6] = f2bf(v1.z); pk.u[7] = f2bf(v1.w);
                a[mt] = pk.v;
            }
#pragma unroll
            for (int ot = 0; ot < 4; ot++) {
                int o = oh * 256 + w * 64 + ot * 16 + ll;
                bf[ot] = *(const short8*)(MlT + o * LD_ + k + lg * 8);
            }
#pragma unroll
            for (int mt = 0; mt < 2; mt++)
#pragma unroll
                for (int ot = 0; ot < 4; ot++)
                    acc[mt][ot] = __builtin_amdgcn_mfma_f32_16x16x32_bf16(a[mt], bf[ot], acc[mt][ot], 0, 0, 0);
        }
#pragma unroll
        for (int mt = 0; mt < 2; mt++)
#pragma unroll
            for (int ot = 0; ot < 4; ot++)
#pragma unroll
                for (int reg = 0; reg < 4; reg++) {
                    int r = r0 + mt * 16 + lg * 4 + reg;
                    if (r < NL_)
                        hlB[(size_t)r * DIM_ + oh * 256 + w * 64 + ot * 16 + ll] = f2bf(acc[mt][ot][reg]);
                }
    }
}

// ==== main: BM=128 x BN=512 — r10 structure, K-window 64 (8 barriers) =======
// 8 waves (2M x 4N), wave tile 64x128, acc[4][8] (128 AGPR).
// A: LDS dbuf 2 x 16KB; each 64-k tile = two 8KB sub-tiles in r10's exact
// 64B-stride swizzled layout (zero new-layout risk). packA runs 2x/window.
// B: fragment-ordered panel, register quads bq0/bq1 rotated 4x per window.
// ONE lgkmcnt(0)+barrier per 64-k window (was per 32-k) -> per-window fixed
// overhead (ds_read first-use, pack chain, barrier resync) amortized 2x.
__global__ __launch_bounds__(512, 2) void k_main2(
    const ushort* __restrict__ hlB, const float* __restrict__ hpb,
    const char* __restrict__ panel, const float* __restrict__ b2,
    const float* __restrict__ W3, const float* __restrict__ b3,
    float* __restrict__ out) {
    __shared__ f32x4 ldsv[2048];            // 32768 B: A dbuf 2 x (2 x 8KB)
    char* lds = (char*)ldsv;
    const int t = threadIdx.x;
    const int n0 = blockIdx.x * 64, s0 = blockIdx.y * 2;
    const int w = t >> 6, lane = t & 63, lg = lane >> 4, ll = lane & 15;
    const int wr = w >> 2, wc = w & 3;      // 2M x 4N wave grid

    // A-staging: thread t owns one 16B chunk per sub-tile (row=t>>2, ks=t&3)
    const int arow = t >> 2, akslot = t & 3;
    int an = n0 + (arow & 63); if (an >= NL_) an = NL_ - 1;
    const ushort* hlsrc = hlB + (size_t)an * DIM_ + akslot * 8;
    const float*  hpsrc = hpb + (s0 + (arow >> 6)) * DIM_ + akslot * 8;
    const int awz = swz(arow, akslot);

    const int abase = swz(wr * 64 + ll, lg);                 // + mt*1024
    const char* bbase = panel + (wc * 8) * 1024 + lane * 16;

    f32x4 acc[4][8] = {};

    auto packSub = [&](int buf, int sub, short8 hv, f32x4 p0, f32x4 p1) {
        float x[8];
#pragma unroll
        for (int e = 0; e < 4; e++) {
            float a0 = bf2f((ushort)hv[e]) + p0[e];
            float a1 = bf2f((ushort)hv[4 + e]) + p1[e];
            x[e]     = a0 > 0.f ? a0 : 0.f;
            x[4 + e] = a1 > 0.f ? a1 : 0.f;
        }
        union { __hip_bfloat162 h2[4]; short8 v; } pk;
#pragma unroll
        for (int e = 0; e < 4; e++)
            pk.h2[e] = __float22bfloat162_rn(make_float2(x[2 * e], x[2 * e + 1]));
        *(short8*)(lds + buf * 16384 + sub * 8192 + awz) = pk.v;
    };

    // ---- prologue: pack window 0 (both subs) into buf 0; preload bq0 ----
    {
        short8 hv0 = *(const short8*)(hlsrc);
        short8 hv1 = *(const short8*)(hlsrc + BK);
        f32x4 p00 = *(const f32x4*)(hpsrc);
        f32x4 p01 = *(const f32x4*)(hpsrc + 4);
        f32x4 p10 = *(const f32x4*)(hpsrc + BK);
        f32x4 p11 = *(const f32x4*)(hpsrc + BK + 4);
        packSub(0, 0, hv0, p00, p01);
        packSub(0, 1, hv1, p10, p11);
        asm volatile("s_waitcnt lgkmcnt(0)" ::: "memory");
        __builtin_amdgcn_s_barrier();
    }
    short8 bq0[4], bq1[4];
#pragma unroll
    for (int j = 0; j < 4; j++) bq0[j] = *(const short8*)(bbase + j * 1024);

    for (int kt2 = 0; kt2 < KT2; kt2++) {
        const char* bs0 = bbase + (2 * kt2) * 32768;       // sub0 B tile
        const char* bs1 = bbase + (2 * kt2 + 1) * 32768;   // sub1 B tile
        const char* A = lds + (kt2 & 1) * 16384;
        // next-window A inputs (global, latency hidden under this window)
        short8 hv0, hv1; f32x4 p00, p01, p10, p11;
        if (kt2 + 1 < KT2) {
            hv0 = *(const short8*)(hlsrc + (2 * kt2 + 2) * BK);
            hv1 = *(const short8*)(hlsrc + (2 * kt2 + 3) * BK);
            p00 = *(const f32x4*)(hpsrc + (2 * kt2 + 2) * BK);
            p01 = *(const f32x4*)(hpsrc + (2 * kt2 + 2) * BK + 4);
            p10 = *(const f32x4*)(hpsrc + (2 * kt2 + 3) * BK);
            p11 = *(const f32x4*)(hpsrc + (2 * kt2 + 3) * BK + 4);
        }
        short8 a[4];
        // ===== sub0 =====
#pragma unroll
        for (int mt = 0; mt < 4; mt++) a[mt] = *(const short8*)(A + abase + mt * 1024);
#pragma unroll
        for (int j = 0; j < 4; j++) bq1[j] = *(const short8*)(bs0 + 4096 + j * 1024);
        __builtin_amdgcn_s_setprio(1);
#pragma unroll
        for (int mt = 0; mt < 4; mt++)
#pragma unroll
            for (int j = 0; j < 4; j++)
                acc[mt][j] = __builtin_amdgcn_mfma_f32_16x16x32_bf16(a[mt], bq0[j], acc[mt][j], 0, 0, 0);
        __builtin_amdgcn_s_setprio(0);
#pragma unroll
        for (int j = 0; j < 4; j++) bq0[j] = *(const short8*)(bs1 + j * 1024);
        __builtin_amdgcn_s_setprio(1);
#pragma unroll
        for (int mt = 0; mt < 4; mt++)
#pragma unroll
            for (int j = 0; j < 4; j++)
                acc[mt][4 + j] = __builtin_amdgcn_mfma_f32_16x16x32_bf16(a[mt], bq1[j], acc[mt][4 + j], 0, 0, 0);
        __builtin_amdgcn_s_setprio(0);
        // ===== sub1 =====
#pragma unroll
        for (int mt = 0; mt < 4; mt++) a[mt] = *(const short8*)(A + 8192 + abase + mt * 1024);
#pragma unroll
        for (int j = 0; j < 4; j++) bq1[j] = *(const short8*)(bs1 + 4096 + j * 1024);
        __builtin_amdgcn_s_setprio(1);
#pragma unroll
        for (int mt = 0; mt < 4; mt++)
#pragma unroll
            for (int j = 0; j < 4; j++)
                acc[mt][j] = __builtin_amdgcn_mfma_f32_16x16x32_bf16(a[mt], bq0[j], acc[mt][j], 0, 0, 0);
        __builtin_amdgcn_s_setprio(0);
        if (kt2 + 1 < KT2)
#pragma unroll
            for (int j = 0; j < 4; j++)
                bq0[j] = *(const short8*)(bbase + (2 * kt2 + 2) * 32768 + j * 1024);
        __builtin_amdgcn_s_setprio(1);
#pragma unroll
        for (int mt = 0; mt < 4; mt++)
#pragma unroll
            for (int j = 0; j < 4; j++)
                acc[mt][4 + j] = __builtin_amdgcn_mfma_f32_16x16x32_bf16(a[mt], bq1[j], acc[mt][4 + j], 0, 0, 0);
        __builtin_amdgcn_s_setprio(0);
        if (kt2 + 1 < KT2) {
            packSub((kt2 + 1) & 1, 0, hv0, p00, p01);
            packSub((kt2 + 1) & 1, 1, hv1, p10, p11);
        }
        // own ds ops drained (reads of buf kt2&1 + packSub writes), then
        // block-wide barrier -> next window's reads are safe.
        asm volatile("s_waitcnt lgkmcnt(0)" ::: "memory");
        __builtin_amdgcn_s_barrier();
    }

    // ---- epilogue: relu(acc+b2)*W3, reduce over o; direct out write ----
    float* logit = (float*)lds;
    if (t < 128) logit[t] = 0.f;
    __syncthreads();
#pragma unroll
    for (int mt = 0; mt < 4; mt++) {
        float p4[4] = { 0.f, 0.f, 0.f, 0.f };
#pragma unroll
        for (int ot = 0; ot < 8; ot++) {
            int o = wc * 128 + ot * 16 + ll;
            float bb = b2[o], w3 = W3[o];
#pragma unroll
            for (int reg = 0; reg < 4; reg++) {
                float v = acc[mt][ot][reg] + bb;
                v = v > 0.f ? v : 0.f;
                p4[reg] += v * w3;
            }
        }
#pragma unroll
        for (int m = 1; m < 16; m <<= 1)
#pragma unroll
            for (int reg = 0; reg < 4; reg++) p4[reg] += __shfl_xor(p4[reg], m, 64);
        if (ll == 0)
#pragma unroll
            for (int reg = 0; reg < 4; reg++)
                atomicAdd(&logit[wr * 64 + mt * 16 + lg * 4 + reg], p4[reg]);
    }
    __syncthreads();
    if (t < 128) {
        int n = n0 + (t & 63);
        int s = s0 + (t >> 6);
        if (n < NL_) out[(size_t)s * NL_ + n] = logit[t] + b3[0];
    }
}

extern "C" void kernel_launch(void* const* d_in, const int* in_sizes, int n_in,
                              void* d_out, int out_size, void* d_ws, size_t ws_size,
                              hipStream_t stream) {
    const float* P_f = (const float*)d_in[0];
    const float* emb = (const float*)d_in[1];
    const float* W_p = (const float*)d_in[2];
    const float* W_l = (const float*)d_in[3];
    const float* W1  = (const float*)d_in[4];
    const float* b1  = (const float*)d_in[5];
    const float* W2  = (const float*)d_in[6];
    const float* b2  = (const float*)d_in[7];
    const float* W3  = (const float*)d_in[8];
    const float* b3  = (const float*)d_in[9];
    const int*   L   = (const int*)d_in[10];
    float* out = (float*)d_out;

    char* ws = (char*)d_ws;
    size_t off = 0;
    auto alloc = [&](size_t bytes) {
        void* p = ws + off;
        off = (off + bytes + 255) & ~(size_t)255;
        return p;
    };
    char*   panel = (char*)alloc((size_t)KSTEPS * 32768);            // 512 KB
    ushort* MlT   = (ushort*)alloc((size_t)OD_ * LD_ * 2);           // 768 KB
    float*  P_e   = (float*)alloc((size_t)S_ * DIM_ * 4);
    float*  hpb   = (float*)alloc((size_t)S_ * DIM_ * 4);
    ushort* hlB   = (ushort*)alloc((size_t)NL_ * DIM_ * 2);          // 5.12 MB

    k_pre1<<<384, 256, 0, stream>>>(W2, W_l, W1, P_f, W_p, panel, MlT, P_e);
    k_pre2<<<378, 256, 0, stream>>>(P_e, W1, b1, emb, L, MlT, hpb, hlB);
    k_main2<<<dim3(NT_M, 32), 512, 0, stream>>>(hlB, hpb, panel, b2, W3, b3, out);
}